// Round 2
// baseline (4247.576 us; speedup 1.0000x reference)
//
#include <hip/hip_runtime.h>
#include <hip/hip_bf16.h>
#include <cstdint>

#define DEV __device__ __forceinline__

DEV float bf2f(__hip_bfloat16 v) { return __bfloat162float(v); }
DEV float rdin(const void* p, size_t i, int isbf) {
  return isbf ? __bfloat162float(((const __hip_bfloat16*)p)[i]) : ((const float*)p)[i];
}
DEV void wrout(void* p, size_t i, float v, int isbf) {
  if (isbf) ((__hip_bfloat16*)p)[i] = __float2bfloat16(v);
  else      ((float*)p)[i] = v;
}

// Detect whether inputs are bf16 or fp32 by examining enc_q_w (~N(0,0.02)).
// As a bf16 stream ~100% of words have exponent in a sane band; as an fp32
// stream the low-mantissa halves are uniform bits (~62% sane). flag=1 -> bf16.
__global__ __launch_bounds__(256) void detect_k(const unsigned short* w, int* flag) {
  __shared__ int cnt[256];
  int tid = threadIdx.x, c = 0;
  for (int i = tid; i < 4096; i += 256) {
    unsigned short v = w[i];
    int e = (v >> 7) & 0xFF;
    if (v == 0 || (e >= 0x60 && e <= 0x9F)) c++;
  }
  cnt[tid] = c;
  __syncthreads();
  for (int s = 128; s > 0; s >>= 1) { if (tid < s) cnt[tid] += cnt[tid + s]; __syncthreads(); }
  if (tid == 0) *flag = (cnt[0] > 3600) ? 1 : 0;
}

// ---------------------------------------------------------------------------
// Generic SIMT implicit-GEMM: C[m,n] = epilogue( sum_k A[m,k]*B[k,n] )
// Tile 64x128, BK=8, 256 threads, 4x8 per thread. M%64==0, N%128==0, K%8==0.
// n encodes (b,pos): b=n>>10, pos=n&1023; blocks never straddle b (128|1024).
// ---------------------------------------------------------------------------
struct AW16 {  // input weights (dtype per flag), row-major [M][K]
  const void* A; int K;
  static constexpr bool fastK = true;
  DEV float load(int m, int k, int b, int isbf) const { return rdin(A, (size_t)m * K + k, isbf); }
};
struct AF32 {  // fp32 ws [b][Crows][ld], row=m, col=k
  const float* A; int Crows; int ld;
  static constexpr bool fastK = true;
  DEV float load(int m, int k, int b, int isbf) const { return A[((size_t)b * Crows + m) * ld + k]; }
};
struct AT32 {  // fp32 ws [b][Crows][ld], row=k, col=m
  const float* A; int Crows; int ld;
  static constexpr bool fastK = false;
  DEV float load(int m, int k, int b, int isbf) const { return A[((size_t)b * Crows + k) * ld + m]; }
};
struct BEnc {  // frame [B][3][512][512]; k=(c,ky,kx) K=768; 16x16 stride-16 patches
  const void* F;
  DEV float load(int k, int n, int isbf) const {
    int b = n >> 10, pos = n & 1023, y = pos >> 5, x = pos & 31;
    int c = k >> 8, r = k & 255, ky = r >> 4, kx = r & 15;
    return rdin(F, (((size_t)(b * 3 + c) << 9) + y * 16 + ky) * 512 + x * 16 + kx, isbf);
  }
};
struct BPlain {  // fp32 ws [B][C][1024]
  const float* X; int C;
  DEV float load(int k, int n, int isbf) const {
    int b = n >> 10, pos = n & 1023;
    return X[((size_t)(b * C + k) << 10) + pos];
  }
};
struct BConv3 {  // fp32 ws [B][C][32][32], 3x3 SAME zero-pad; k=(c,dy,dx)
  const float* X; int C;
  DEV float load(int k, int n, int isbf) const {
    int b = n >> 10, pos = n & 1023, y = pos >> 5, x = pos & 31;
    int c = k / 9, r = k - c * 9, dy = r / 3, dx = r - dy * 3;
    int iy = y + dy - 1, ix = x + dx - 1;
    if ((unsigned)iy >= 32u || (unsigned)ix >= 32u) return 0.f;
    return X[((size_t)(b * C + c) << 10) + iy * 32 + ix];
  }
};

struct CW {  // epilogue: v*scale; +bias[m]; exp; *mask; *nscale[n]; relu -> fp32 ws
  float* out;
  const void* bias;   // [M] input dtype, or null
  const void* mask;   // [B][512][512] input dtype sampled at (16y,16x), or null
  const float* nscale;  // fp32 [N] or null
  int Ctot; int c_off; int nstr; int n_off; float scale; int relu; int do_exp;
  DEV void store(int m, int n, float v, int isbf) const {
    v *= scale;
    if (bias)   v += rdin(bias, m, isbf);
    if (do_exp) v = __expf(v);
    int b = n >> 10, pos = n & 1023;
    if (mask) {
      int y = pos >> 5, x = pos & 31;
      v *= rdin(mask, ((size_t)(b * 512 + y * 16) << 9) + x * 16, isbf);
    }
    if (nscale) v *= nscale[n];
    if (relu)   v = fmaxf(v, 0.f);
    out[(size_t)(b * Ctot + c_off + m) * (size_t)nstr + n_off + pos] = v;
  }
};

template <class AP, class BP>
__global__ __launch_bounds__(256) void gemm_k(AP ap, BP bp, CW cw, const int* dflag,
                                              int M, int N, int K) {
  __shared__ alignas(16) float As[8][68];
  __shared__ alignas(16) float Bs[8][132];
  int isbf = *dflag;
  int tid = threadIdx.x;
  int tx = tid & 15, ty = tid >> 4;
  int n0 = blockIdx.x * 128, m0 = blockIdx.y * 64;
  int bb = n0 >> 10;
  float acc[4][8];
#pragma unroll
  for (int i = 0; i < 4; i++)
#pragma unroll
    for (int j = 0; j < 8; j++) acc[i][j] = 0.f;

  for (int k0 = 0; k0 < K; k0 += 8) {
    if constexpr (AP::fastK) {
#pragma unroll
      for (int i = 0; i < 2; i++) {
        int idx = tid + i * 256; int kk = idx & 7, mm = idx >> 3;
        As[kk][mm] = ap.load(m0 + mm, k0 + kk, bb, isbf);
      }
    } else {
#pragma unroll
      for (int i = 0; i < 2; i++) {
        int idx = tid + i * 256; int mm = idx & 63, kk = idx >> 6;
        As[kk][mm] = ap.load(m0 + mm, k0 + kk, bb, isbf);
      }
    }
#pragma unroll
    for (int i = 0; i < 4; i++) {
      int idx = tid + i * 256; int nn = idx & 127, kk = idx >> 7;
      Bs[kk][nn] = bp.load(k0 + kk, n0 + nn, isbf);
    }
    __syncthreads();
#pragma unroll
    for (int kk = 0; kk < 8; kk++) {
      float4 a  = *(const float4*)&As[kk][ty * 4];
      float4 b0 = *(const float4*)&Bs[kk][tx * 4];
      float4 b1 = *(const float4*)&Bs[kk][64 + tx * 4];
      float av[4] = {a.x, a.y, a.z, a.w};
      float bv[8] = {b0.x, b0.y, b0.z, b0.w, b1.x, b1.y, b1.z, b1.w};
#pragma unroll
      for (int i = 0; i < 4; i++)
#pragma unroll
        for (int j = 0; j < 8; j++) acc[i][j] = fmaf(av[i], bv[j], acc[i][j]);
    }
    __syncthreads();
  }
#pragma unroll
  for (int i = 0; i < 4; i++) {
    int m = m0 + ty * 4 + i;
#pragma unroll
    for (int j = 0; j < 8; j++) {
      int n = n0 + ((j < 4) ? (tx * 4 + j) : (64 + tx * 4 + j - 4));
      cw.store(m, n, acc[i][j], isbf);
    }
  }
}

// mask + l2norm over 64 key channels; scatter into mem/query key buffer
__global__ __launch_bounds__(256) void keyfix_k(const float* kraw, const void* mask,
                                                float* outk, int nstr, int n_off,
                                                const int* dflag) {
  int isbf = *dflag;
  int n = blockIdx.x * 256 + threadIdx.x;  // 8192
  int b = n >> 10, pos = n & 1023, y = pos >> 5, x = pos & 31;
  float mv = 1.f;
  if (mask) mv = rdin(mask, ((size_t)(b * 512 + y * 16) << 9) + x * 16, isbf);
  float ss = 0.f;
  for (int c = 0; c < 64; c++) {
    float v = kraw[((size_t)(b * 64 + c) << 10) + pos] * mv;
    ss += v * v;
  }
  float inv = 1.f / fmaxf(sqrtf(ss), 1e-12f);
  for (int c = 0; c < 64; c++) {
    float v = kraw[((size_t)(b * 64 + c) << 10) + pos] * mv;
    outk[(size_t)(b * 64 + c) * (size_t)nstr + n_off + pos] = v * inv;
  }
}

// column sums of exp'ed P -> 1/sum (per query). P is group-local (nb batches).
__global__ __launch_bounds__(256) void stats_k(const float* P, float* rsinv) {
  __shared__ float red[4][64];
  int tid = threadIdx.x;
  int qi = tid & 63, ms = tid >> 6;
  int q = blockIdx.x * 64 + qi;
  int b = q >> 10, qq = q & 1023;
  const float* col = P + ((size_t)b * 2048 << 10) + qq;
  float s = 0.f;
  for (int m = ms; m < 2048; m += 4) s += col[(size_t)m << 10];
  red[ms][qi] = s;
  __syncthreads();
  if (tid < 64) {
    float t = red[0][tid] + red[1][tid] + red[2][tid] + red[3][tid];
    rsinv[blockIdx.x * 64 + tid] = 1.f / t;
  }
}

// rep_feat = l2norm(dec_feat) -> out; cls 1x1 conv -> logits (fp32 ws)
__global__ __launch_bounds__(256) void repcls_k(const float* decf, const void* cwgt,
                                                const void* cbias, void* out_rep,
                                                float* logits, const int* dflag) {
  int isbf = *dflag;
  int n = blockIdx.x * 256 + threadIdx.x;  // 8192
  int b = n >> 10, pos = n & 1023;
  const float* src = decf + ((size_t)(b * 256) << 10) + pos;
  float ss = 0.f, a0 = 0.f, a1 = 0.f;
  for (int c = 0; c < 256; c++) {
    float v = src[(size_t)c << 10];
    ss += v * v;
    a0 = fmaf(v, rdin(cwgt, c, isbf), a0);
    a1 = fmaf(v, rdin(cwgt, 256 + c, isbf), a1);
  }
  float inv = 1.f / fmaxf(sqrtf(ss), 1e-12f);
  for (int c = 0; c < 256; c++) {
    float v = src[(size_t)c << 10];
    wrout(out_rep, ((size_t)(b * 256 + c) << 10) + pos, v * inv, isbf);
  }
  logits[((size_t)(b * 2) << 10) + pos]     = a0 + rdin(cbias, 0, isbf);
  logits[((size_t)(b * 2 + 1) << 10) + pos] = a1 + rdin(cbias, 1, isbf);
}

// bilinear 32x32 -> 512x512 (jax half-pixel; edge renorm == clamp for 2-tap)
__global__ __launch_bounds__(256) void resize_k(const float* logits, void* out,
                                                size_t ebase, const int* dflag) {
  int isbf = *dflag;
  int idx = blockIdx.x * 256 + threadIdx.x;  // 8*2*512*512
  int ox = idx & 511, oy = (idx >> 9) & 511, c = (idx >> 18) & 1, b = idx >> 19;
  float fy = (oy + 0.5f) * 0.0625f - 0.5f;
  float fx = (ox + 0.5f) * 0.0625f - 0.5f;
  int y0 = (int)floorf(fy), x0 = (int)floorf(fx);
  float wy = fy - y0, wx = fx - x0;
  int y0c = max(y0, 0), y1c = min(y0 + 1, 31);
  int x0c = max(x0, 0), x1c = min(x0 + 1, 31);
  const float* L = logits + ((size_t)(b * 2 + c) << 10);
  float v00 = L[y0c * 32 + x0c], v01 = L[y0c * 32 + x1c];
  float v10 = L[y1c * 32 + x0c], v11 = L[y1c * 32 + x1c];
  float v = (1.f - wy) * ((1.f - wx) * v00 + wx * v01) + wy * ((1.f - wx) * v10 + wx * v11);
  wrout(out, ebase + (size_t)idx, v, isbf);
}

extern "C" void kernel_launch(void* const* d_in, const int* in_sizes, int n_in,
                              void* d_out, int out_size, void* d_ws, size_t ws_size,
                              hipStream_t stream) {
  const void* query  = d_in[0];
  const void* prev   = d_in[1];
  const void* prevM  = d_in[2];
  const void* first  = d_in[3];
  const void* firstM = d_in[4];
  const void* encQw  = d_in[5];
  const void* encQb  = d_in[6];
  const void* encMw  = d_in[7];
  const void* encMb  = d_in[8];
  const void* keyW   = d_in[9];
  const void* keyB   = d_in[10];
  const void* valW   = d_in[11];
  const void* valB   = d_in[12];
  const void* dec1W  = d_in[13];
  const void* dec1B  = d_in[14];
  const void* dec2W  = d_in[15];
  const void* dec2B  = d_in[16];
  const void* clsW   = d_in[17];
  const void* clsB   = d_in[18];

  // Lean ws layout (floats). Total = 14,688,272 floats ~= 56.03 MB.
  float* ws = (float*)d_ws;
  float* memk  = ws;                  // 1,048,576  [8][64][2048]
  float* memv  = ws + 1048576;        // 4,194,304  [8][256][2048]
  float* qk    = ws + 5242880;        //   524,288  [8][64][1024]
  float* fused = ws + 5767168;        // 4,194,304  [8][512][1024] (qv | mem_read)
  float* rsinv = ws + 9961472;        //     8,192
  int*   dflag = (int*)(ws + 9969664);//        16
  float* R     = ws + 9969680;        // 4,718,592 shared scratch region
  float* feat  = R;                   // encode: [8][512][1024]
  float* kraw  = R + 4194304;         // encode: [8][64][1024]
  float* Pbuf  = R;                   // attn:   [2][2048][1024]
  float* dbuf  = R;                   // dec:    [8][256][1024]
  float* decf  = R + 2097152;         // dec:    [8][256][1024]
  float* logits= R + 4194304;         // dec:    [8][2][1024]

  dim3 blk(256);
  detect_k<<<dim3(1), blk, 0, stream>>>((const unsigned short*)encQw, dflag);

  struct Frame {
    const void *img, *mask, *ew, *eb;
    float* kdst; int knstr, koff;
    float* vdst; int vCtot, vcoff, vnstr, voff;
  };
  Frame fr[3] = {
      {first, firstM, encMw, encMb, memk, 2048, 0,    memv, 256, 0, 2048, 0},
      {prev,  prevM,  encMw, encMb, memk, 2048, 1024, memv, 256, 0, 2048, 1024},
      {query, nullptr, encQw, encQb, qk,  1024, 0,    fused, 512, 0, 1024, 0},
  };
  for (int f = 0; f < 3; f++) {
    CW cwE{feat, fr[f].eb, nullptr, nullptr, 512, 0, 1024, 0, 1.f, 1, 0};
    gemm_k<AW16, BEnc><<<dim3(64, 8), blk, 0, stream>>>(AW16{fr[f].ew, 768}, BEnc{fr[f].img}, cwE, dflag, 512, 8192, 768);
    CW cwK{kraw, keyB, nullptr, nullptr, 64, 0, 1024, 0, 1.f, 0, 0};
    gemm_k<AW16, BPlain><<<dim3(64, 1), blk, 0, stream>>>(AW16{keyW, 512}, BPlain{feat, 512}, cwK, dflag, 64, 8192, 512);
    CW cwV{fr[f].vdst, valB, fr[f].mask, nullptr, fr[f].vCtot, fr[f].vcoff, fr[f].vnstr, fr[f].voff, 1.f, 0, 0};
    gemm_k<AW16, BPlain><<<dim3(64, 4), blk, 0, stream>>>(AW16{valW, 512}, BPlain{feat, 512}, cwV, dflag, 256, 8192, 512);
    keyfix_k<<<dim3(32), blk, 0, stream>>>(kraw, fr[f].mask, fr[f].kdst, fr[f].knstr, fr[f].koff, dflag);
  }

  // Attention in 4 groups of 2 batches; P = exp(score) materialized per group.
  for (int g = 0; g < 4; g++) {
    int b0 = 2 * g;
    // P[b][m][q] = exp( (memk[b,:,m] . qk[b,:,q]) / 8 )  (|s|<=1/8: no max needed)
    CW cwS{Pbuf, nullptr, nullptr, nullptr, 2048, 0, 1024, 0, 0.125f, 0, 1};
    gemm_k<AT32, BPlain><<<dim3(16, 32), blk, 0, stream>>>(
        AT32{memk + (size_t)b0 * 64 * 2048, 64, 2048}, BPlain{qk + ((size_t)b0 << 16), 64},
        cwS, dflag, 2048, 2048, 64);
    stats_k<<<dim3(32), blk, 0, stream>>>(Pbuf, rsinv + (size_t)b0 * 1024);
    // mem_read[b][c][q] = rsinv * sum_m memv[b,c,m] * P[b][m][q] -> fused rows 256..511
    CW cwR{fused + (size_t)b0 * 512 * 1024, nullptr, nullptr, rsinv + (size_t)b0 * 1024,
           512, 256, 1024, 0, 1.f, 0, 0};
    gemm_k<AF32, BPlain><<<dim3(16, 4), blk, 0, stream>>>(
        AF32{memv + (size_t)b0 * 256 * 2048, 256, 2048}, BPlain{Pbuf, 2048},
        cwR, dflag, 256, 2048, 2048);
  }

  CW cwD1{dbuf, dec1B, nullptr, nullptr, 256, 0, 1024, 0, 1.f, 1, 0};
  gemm_k<AW16, BConv3><<<dim3(64, 4), blk, 0, stream>>>(AW16{dec1W, 4608}, BConv3{fused, 512}, cwD1, dflag, 256, 8192, 4608);
  CW cwD2{decf, dec2B, nullptr, nullptr, 256, 0, 1024, 0, 1.f, 1, 0};
  gemm_k<AW16, BConv3><<<dim3(64, 4), blk, 0, stream>>>(AW16{dec2W, 2304}, BConv3{dbuf, 256}, cwD2, dflag, 256, 8192, 2304);

  repcls_k<<<dim3(32), blk, 0, stream>>>(decf, clsW, clsB, d_out, logits, dflag);
  resize_k<<<dim3(16384), blk, 0, stream>>>(logits, d_out, (size_t)2097152, dflag);
}

// Round 3
// 694.076 us; speedup vs baseline: 6.1198x; 6.1198x over previous
//
#include <hip/hip_runtime.h>
#include <hip/hip_bf16.h>
#include <cstdint>

#define DEV __device__ __forceinline__

typedef __attribute__((ext_vector_type(8))) short short8;
typedef __attribute__((ext_vector_type(4))) float f32x4;

DEV float b2f(unsigned short u) { union { unsigned int i; float f; } x; x.i = (unsigned)u << 16; return x.f; }
DEV unsigned short f2b(float f) { __hip_bfloat16 h = __float2bfloat16(f); return *(unsigned short*)&h; }
DEV float rdin(const void* p, size_t i, int isbf) {
  return isbf ? __bfloat162float(((const __hip_bfloat16*)p)[i]) : ((const float*)p)[i];
}
DEV void wrout(void* p, size_t i, float v, int isbf) {
  if (isbf) ((__hip_bfloat16*)p)[i] = __float2bfloat16(v);
  else      ((float*)p)[i] = v;
}
// 8 consecutive source elems -> bf16 bits (vectorized for both dtypes)
DEV short8 ld8(const void* p, size_t idx, int isbf) {
  if (isbf) return *(const short8*)((const unsigned short*)p + idx);
  const float* f = (const float*)p + idx;
  float4 x = *(const float4*)f, y = *(const float4*)(f + 4);
  short8 r;
  r[0] = f2b(x.x); r[1] = f2b(x.y); r[2] = f2b(x.z); r[3] = f2b(x.w);
  r[4] = f2b(y.x); r[5] = f2b(y.y); r[6] = f2b(y.z); r[7] = f2b(y.w);
  return r;
}

// dtype detector (worked in round 2): bf16 stream -> ~100% sane exponents
__global__ __launch_bounds__(256) void detect_k(const unsigned short* w, int* flag) {
  __shared__ int cnt[256];
  int tid = threadIdx.x, c = 0;
  for (int i = tid; i < 4096; i += 256) {
    unsigned short v = w[i];
    int e = (v >> 7) & 0xFF;
    if (v == 0 || (e >= 0x60 && e <= 0x9F)) c++;
  }
  cnt[tid] = c;
  __syncthreads();
  for (int s = 128; s > 0; s >>= 1) { if (tid < s) cnt[tid] += cnt[tid + s]; __syncthreads(); }
  if (tid == 0) *flag = (cnt[0] > 3600) ? 1 : 0;
}

// ---------------- providers: load8(row, k0, b, isbf) -> 8 bf16 along k ----------------
struct PWgt {  // input weights [M][K], dtype per flag, k contiguous
  const void* W; int K;
  DEV short8 load8(int m, int k, int b, int isbf) const { return ld8(W, (size_t)m * K + k, isbf); }
};
struct PWs {   // bf16 ws tensor: addr = b*bs + r*rs + k (k contiguous)
  const unsigned short* X; int rs; size_t bs;
  DEV short8 load8(int r, int k, int b, int) const {
    return *(const short8*)(X + (size_t)b * bs + (size_t)r * rs + k);
  }
};
struct PEnc {  // frame [B][3][512][512]; k=(c,ky,kx) K=768; token r -> 16x16 patch
  const void* F;
  DEV short8 load8(int r, int k, int b, int isbf) const {
    int pos = r & 1023, y = pos >> 5, x = pos & 31;
    int c = k >> 8, rem = k & 255, ky = rem >> 4, kx = rem & 15;
    return ld8(F, ((((size_t)(b * 3 + c) << 9) + y * 16 + ky) << 9) + x * 16 + kx, isbf);
  }
};
struct PC3B {  // 3x3 SAME im2col over token-major bf16 act [tok][C]; k=(t=(dy,dx), c)
  const unsigned short* X; int C, shift;
  DEV short8 load8(int r, int k, int b, int) const {
    int t = k >> shift, c0 = k & (C - 1);
    int dy = t / 3, dx = t - dy * 3;
    int pos = r & 1023, y = pos >> 5, x = pos & 31;
    int iy = y + dy - 1, ix = x + dx - 1;
    if ((unsigned)iy >= 32u || (unsigned)ix >= 32u) { short8 z = {0,0,0,0,0,0,0,0}; return z; }
    return *(const short8*)(X + (size_t)(b * 1024 + iy * 32 + ix) * C + c0);
  }
};

struct Epi {  // v*scale; +bias[m]; exp; *mask(b,pos(n)); *rscale[b*1024+m]; relu -> bf16 ws
  unsigned short* out; const void* bias; const void* mask; const float* rscale;
  size_t obs, ors, ocs, obase; unsigned nmask; float scale; int relu, doexp;
  DEV void store(int m, int n, int b, float v, int isbf) const {
    v *= scale;
    if (bias)  v += rdin(bias, m, isbf);
    if (doexp) v = __expf(v);
    if (mask) {
      int pos = n & 1023;
      v *= rdin(mask, ((size_t)(b * 512 + (pos >> 5) * 16) << 9) + (pos & 31) * 16, isbf);
    }
    if (rscale) v *= rscale[b * 1024 + m];
    if (relu) v = fmaxf(v, 0.f);
    out[obase + (size_t)b * obs + (size_t)m * ors + (size_t)(n & nmask) * ocs] = f2b(v);
  }
};

// ---------------- MFMA GEMM: tile 64(M) x 128(N), BK=32, 256 thr = 4 waves ----------------
template <class PA, class PB>
__global__ __launch_bounds__(256) void mgemm(PA pa, PB pb, Epi ep, int K, const int* dflag) {
  __shared__ unsigned short As[64 * 40];   // row stride 40 shorts (pad)
  __shared__ unsigned short Bs[128 * 40];
  int isbf = *dflag;
  int tid = threadIdx.x;
  int n0 = blockIdx.x * 128, m0 = blockIdx.y * 64;
  int b = (gridDim.z > 1) ? blockIdx.z : (n0 >> 10);
  int lane = tid & 63, wv = tid >> 6, col16 = lane & 15, quad = lane >> 4;

  f32x4 acc[4][2];
#pragma unroll
  for (int mt = 0; mt < 4; mt++)
#pragma unroll
    for (int nt = 0; nt < 2; nt++)
#pragma unroll
      for (int r = 0; r < 4; r++) acc[mt][nt][r] = 0.f;

  int arow = tid >> 2, akc = (tid & 3) << 3;   // A: 256 chunks of 8 (64 rows x 4)
  int brow = tid >> 2, bkc = (tid & 3) << 3;   // B: 512 chunks (rows 0..63 then 64..127)

  short8 av = pa.load8(m0 + arow, akc, b, isbf);
  short8 bv0 = pb.load8(n0 + brow, bkc, b, isbf);
  short8 bv1 = pb.load8(n0 + 64 + brow, bkc, b, isbf);

  for (int k0 = 0; k0 < K; k0 += 32) {
    __syncthreads();  // prior iteration's frag reads done
    *(short8*)&As[arow * 40 + akc] = av;
    *(short8*)&Bs[brow * 40 + bkc] = bv0;
    *(short8*)&Bs[(64 + brow) * 40 + bkc] = bv1;
    __syncthreads();
    int kn = (k0 + 32 < K) ? k0 + 32 : k0;  // prefetch next tile under MFMA
    av = pa.load8(m0 + arow, kn + akc, b, isbf);
    bv0 = pb.load8(n0 + brow, kn + bkc, b, isbf);
    bv1 = pb.load8(n0 + 64 + brow, kn + bkc, b, isbf);

    short8 af[4], bfr[2];
#pragma unroll
    for (int mt = 0; mt < 4; mt++) af[mt] = *(short8*)&As[(mt * 16 + col16) * 40 + quad * 8];
#pragma unroll
    for (int nt = 0; nt < 2; nt++) bfr[nt] = *(short8*)&Bs[(wv * 32 + nt * 16 + col16) * 40 + quad * 8];
#pragma unroll
    for (int mt = 0; mt < 4; mt++)
#pragma unroll
      for (int nt = 0; nt < 2; nt++)
        acc[mt][nt] = __builtin_amdgcn_mfma_f32_16x16x32_bf16(af[mt], bfr[nt], acc[mt][nt], 0, 0, 0);
  }

#pragma unroll
  for (int mt = 0; mt < 4; mt++)
#pragma unroll
    for (int nt = 0; nt < 2; nt++)
#pragma unroll
      for (int r = 0; r < 4; r++)
        ep.store(m0 + mt * 16 + quad * 4 + r, n0 + wv * 32 + nt * 16 + col16, b, acc[mt][nt][r], isbf);
}

// conv3 weight reorder: dst[m][t*C+c] = src[(m*C+c)*9 + t]  (dst linear = idx)
__global__ __launch_bounds__(256) void wreorder_k(const void* src, unsigned short* dst,
                                                  int C, int total, const int* dflag) {
  int idx = blockIdx.x * 256 + threadIdx.x;
  if (idx >= total) return;
  int isbf = *dflag;
  int nine_c = 9 * C;
  int m = idx / nine_c; int r = idx - m * nine_c;
  int t = r / C; int c = r - t * C;
  dst[idx] = f2b(rdin(src, (size_t)(m * C + c) * 9 + t, isbf));
}

// mask + l2norm over 64 key channels (kraw token-major) -> token-major dst
__global__ __launch_bounds__(256) void keyfix_k(const unsigned short* kraw, const void* mask,
                                                unsigned short* out, size_t bs, int base,
                                                const int* dflag) {
  int isbf = *dflag;
  int n = blockIdx.x * 256 + threadIdx.x;  // 8192 tokens
  int b = n >> 10, pos = n & 1023;
  float mv = 1.f;
  if (mask) mv = rdin(mask, ((size_t)(b * 512 + (pos >> 5) * 16) << 9) + (pos & 31) * 16, isbf);
  const unsigned short* src = kraw + (size_t)n * 64;
  float v[64], ss = 0.f;
#pragma unroll
  for (int c = 0; c < 64; c++) { v[c] = b2f(src[c]) * mv; ss += v[c] * v[c]; }
  float inv = 1.f / fmaxf(sqrtf(ss), 1e-12f);
  unsigned short* dst = out + (size_t)b * bs + (size_t)(base + pos) * 64;
#pragma unroll
  for (int c = 0; c < 64; c++) dst[c] = f2b(v[c] * inv);
}

// P row sums (bf16 [8192][2048]) -> 1/sum
__global__ __launch_bounds__(256) void stats_k(const unsigned short* P, float* rsinv) {
  int tid = threadIdx.x, lane = tid & 63, wv = tid >> 6;
  int row = blockIdx.x * 4 + wv;
  const unsigned short* p = P + (size_t)row * 2048;
  float s = 0.f;
#pragma unroll
  for (int c = 0; c < 4; c++) {
    short8 v = *(const short8*)(p + c * 512 + lane * 8);
#pragma unroll
    for (int j = 0; j < 8; j++) s += b2f((unsigned short)v[j]);
  }
#pragma unroll
  for (int off = 32; off > 0; off >>= 1) s += __shfl_down(s, off);
  if (lane == 0) rsinv[row] = 1.f / s;
}

// rep_feat = l2norm(decf) -> d_out (NCHW); cls 1x1 -> fp32 logits. One wave per token.
__global__ __launch_bounds__(256) void repcls_k(const unsigned short* decf, const void* cwgt,
                                                const void* cbias, void* out_rep,
                                                float* logits, const int* dflag) {
  int isbf = *dflag;
  int tid = threadIdx.x, lane = tid & 63, wv = tid >> 6;
  int tok = blockIdx.x * 4 + wv;
  int b = tok >> 10, pos = tok & 1023;
  const unsigned short* src = decf + (size_t)tok * 256;
  int c0 = lane * 4;
  float v[4], ss = 0.f, a0 = 0.f, a1 = 0.f;
#pragma unroll
  for (int j = 0; j < 4; j++) {
    float x = b2f(src[c0 + j]);
    v[j] = x; ss += x * x;
    a0 = fmaf(x, rdin(cwgt, c0 + j, isbf), a0);
    a1 = fmaf(x, rdin(cwgt, 256 + c0 + j, isbf), a1);
  }
#pragma unroll
  for (int off = 32; off > 0; off >>= 1) {
    ss += __shfl_down(ss, off); a0 += __shfl_down(a0, off); a1 += __shfl_down(a1, off);
  }
  ss = __shfl(ss, 0); a0 = __shfl(a0, 0); a1 = __shfl(a1, 0);
  float inv = 1.f / fmaxf(sqrtf(ss), 1e-12f);
#pragma unroll
  for (int j = 0; j < 4; j++)
    wrout(out_rep, ((size_t)(b * 256 + c0 + j) << 10) + pos, v[j] * inv, isbf);
  if (lane == 0) {
    logits[((size_t)(b * 2) << 10) + pos]     = a0 + rdin(cbias, 0, isbf);
    logits[((size_t)(b * 2 + 1) << 10) + pos] = a1 + rdin(cbias, 1, isbf);
  }
}

// bilinear 32x32 -> 512x512 (jax half-pixel; edge renorm == clamp for 2-tap)
__global__ __launch_bounds__(256) void resize_k(const float* logits, void* out,
                                                size_t ebase, const int* dflag) {
  int isbf = *dflag;
  int idx = blockIdx.x * 256 + threadIdx.x;
  int ox = idx & 511, oy = (idx >> 9) & 511, c = (idx >> 18) & 1, b = idx >> 19;
  float fy = (oy + 0.5f) * 0.0625f - 0.5f;
  float fx = (ox + 0.5f) * 0.0625f - 0.5f;
  int y0 = (int)floorf(fy), x0 = (int)floorf(fx);
  float wy = fy - y0, wx = fx - x0;
  int y0c = max(y0, 0), y1c = min(y0 + 1, 31);
  int x0c = max(x0, 0), x1c = min(x0 + 1, 31);
  const float* L = logits + ((size_t)(b * 2 + c) << 10);
  float v00 = L[y0c * 32 + x0c], v01 = L[y0c * 32 + x1c];
  float v10 = L[y1c * 32 + x0c], v11 = L[y1c * 32 + x1c];
  float v = (1.f - wy) * ((1.f - wx) * v00 + wx * v01) + wy * ((1.f - wx) * v10 + wx * v11);
  wrout(out, ebase + (size_t)idx, v, isbf);
}

extern "C" void kernel_launch(void* const* d_in, const int* in_sizes, int n_in,
                              void* d_out, int out_size, void* d_ws, size_t ws_size,
                              hipStream_t stream) {
  const void* query  = d_in[0];
  const void* prev   = d_in[1];
  const void* prevM  = d_in[2];
  const void* first  = d_in[3];
  const void* firstM = d_in[4];
  const void* encQw  = d_in[5];
  const void* encQb  = d_in[6];
  const void* encMw  = d_in[7];
  const void* encMb  = d_in[8];
  const void* keyW   = d_in[9];
  const void* keyB   = d_in[10];
  const void* valW   = d_in[11];
  const void* valB   = d_in[12];
  const void* dec1W  = d_in[13];
  const void* dec1B  = d_in[14];
  const void* dec2W  = d_in[15];
  const void* dec2B  = d_in[16];
  const void* clsW   = d_in[17];
  const void* clsB   = d_in[18];

  // ws layout in u16 units (~53.6 MB total; round-2's 56 MB layout fit)
  unsigned short* W = (unsigned short*)d_ws;
  unsigned short* fused = W;                  // [8192][512]           4,194,304
  unsigned short* memv  = W + 4194304;        // [8][256][2048]        4,194,304
  unsigned short* memk  = W + 8388608;        // [8][2048][64]         1,048,576
  unsigned short* qk    = W + 9437184;        // [8][1024][64]           524,288
  float* rsinv = (float*)(W + 9961472);       // 8192 f32
  float* logits = rsinv + 8192;               // 16384 f32
  int* dflag = (int*)(logits + 16384);
  unsigned short* E = W + 10010640;           // 16,777,216 u16 scratch
  unsigned short* feat = E;                   // encode: [8192][512]
  unsigned short* kraw = E + 4194304;         // encode: [8192][64]
  unsigned short* P    = E;                   // attn:   [8][1024][2048] bf16 (32MB)
  unsigned short* dbuf = E;                   // dec:    [8192][256]
  unsigned short* decf = E + 2097152;         // dec:    [8192][256]
  unsigned short* wr1  = E + 4194304;         // dec1W reordered [256][4608]
  unsigned short* wr2  = E + 5373952;         // dec2W reordered [256][2304]

  dim3 blk(256);
  detect_k<<<dim3(1), blk, 0, stream>>>((const unsigned short*)encQw, dflag);

  struct Frame { const void *img, *mask, *ew, *eb; unsigned short* kdst; size_t kbs; int kbase; };
  Frame fr[3] = {
      {first, firstM, encMw, encMb, memk, 131072, 0},
      {prev,  prevM,  encMw, encMb, memk, 131072, 1024},
      {query, nullptr, encQw, encQb, qk,  65536,  0},
  };
  for (int f = 0; f < 3; f++) {
    Epi eF{feat, fr[f].eb, nullptr, nullptr, 0, 1, 512, 0, ~0u, 1.f, 1, 0};
    mgemm<PWgt, PEnc><<<dim3(64, 8, 1), blk, 0, stream>>>(PWgt{fr[f].ew, 768}, PEnc{fr[f].img}, eF, 768, dflag);
    Epi eK{kraw, keyB, nullptr, nullptr, 0, 1, 64, 0, ~0u, 1.f, 0, 0};
    mgemm<PWgt, PWs><<<dim3(64, 1, 1), blk, 0, stream>>>(PWgt{keyW, 512}, PWs{feat, 512, 0}, eK, 512, dflag);
    if (f < 2) {
      Epi eV{memv, valB, fr[f].mask, nullptr, 524288, 2048, 1, (size_t)(fr[f].kbase * 1024ULL) / 1024 * 1024, 1023u, 1.f, 0, 0};
      eV.obase = (size_t)fr[f].kbase;  // f*1024 column offset within [b][c][2048]
      mgemm<PWgt, PWs><<<dim3(64, 4, 1), blk, 0, stream>>>(PWgt{valW, 512}, PWs{feat, 512, 0}, eV, 512, dflag);
    } else {
      Epi eV{fused, valB, nullptr, nullptr, 0, 1, 512, 0, ~0u, 1.f, 0, 0};
      mgemm<PWgt, PWs><<<dim3(64, 4, 1), blk, 0, stream>>>(PWgt{valW, 512}, PWs{feat, 512, 0}, eV, 512, dflag);
    }
    keyfix_k<<<dim3(32), blk, 0, stream>>>(kraw, fr[f].mask, fr[f].kdst, fr[f].kbs, fr[f].kbase, dflag);
  }

  // S: P[b][q][m] = exp(0.125 * qk[b,q,:] . memk[b,m,:])   (|dot|<=1: no max-sub needed)
  {
    Epi eS{P, nullptr, nullptr, nullptr, 2097152, 2048, 1, 0, ~0u, 0.125f, 0, 1};
    mgemm<PWs, PWs><<<dim3(16, 16, 8), blk, 0, stream>>>(PWs{qk, 64, 65536}, PWs{memk, 64, 131072}, eS, 64, dflag);
  }
  stats_k<<<dim3(2048), blk, 0, stream>>>(P, rsinv);
  // read: fused[b*1024+q][256+c] = rsinv[q] * sum_m P[q][m] * memv[b][c][m]
  {
    Epi eR{fused, nullptr, nullptr, rsinv, 524288, 512, 1, 256, ~0u, 1.f, 0, 0};
    mgemm<PWs, PWs><<<dim3(2, 16, 8), blk, 0, stream>>>(PWs{P, 2048, 2097152}, PWs{memv, 2048, 524288}, eR, 2048, dflag);
  }

  wreorder_k<<<dim3(4608), blk, 0, stream>>>(dec1W, wr1, 512, 256 * 4608, dflag);
  wreorder_k<<<dim3(2304), blk, 0, stream>>>(dec2W, wr2, 256, 256 * 2304, dflag);

  Epi eD1{dbuf, dec1B, nullptr, nullptr, 0, 1, 256, 0, ~0u, 1.f, 1, 0};
  mgemm<PWs, PC3B><<<dim3(64, 4, 1), blk, 0, stream>>>(PWs{wr1, 4608, 0}, PC3B{fused, 512, 9}, eD1, 4608, dflag);
  Epi eD2{decf, dec2B, nullptr, nullptr, 0, 1, 256, 0, ~0u, 1.f, 1, 0};
  mgemm<PWs, PC3B><<<dim3(64, 4, 1), blk, 0, stream>>>(PWs{wr2, 2304, 0}, PC3B{dbuf, 256, 8}, eD2, 2304, dflag);

  repcls_k<<<dim3(2048), blk, 0, stream>>>(decf, clsW, clsB, d_out, logits, dflag);
  resize_k<<<dim3(16384), blk, 0, stream>>>(logits, d_out, (size_t)2097152, dflag);
}